// Round 8
// baseline (38100.516 us; speedup 1.0000x reference)
//
#include <hip/hip_runtime.h>
#include <math.h>
#include <stdint.h>

// VQ-VAE vector quantizer (inference), MI355X / gfx950.
// N=32768 tokens, D=256, K=8192 codes.
// Round-8: bf16-MFMA shortlist + exact-f32 rescue.
//   - distances bin to ulp(S)~3e-5; near the row min the code density is
//     ~1.6 codes / 6e-4 (sparse tail) => single bf16 product + MARGIN=6e-4
//     shortlist provably contains the reference argmin (2*eps+bin ~ 2.8e-4).
//   - rescue re-verifies candidates with the bit-proven fmaf chain
//     (identical to rounds 3-7, absmax 0.0) incl. first-index tie-break.
//   - f32 VALU path kept verbatim (round-6, passing) as fallback when
//     ws_size < 6.9MB (MFMA path needs EhT + candidate buffers).

#define N_TOK   32768
#define DIM     256
#define K_EMB   8192

typedef __attribute__((ext_vector_type(8))) short short8v;  // 8 bf16 (4 VGPR)
typedef __attribute__((ext_vector_type(4))) float f32x4;
typedef __attribute__((ext_vector_type(2))) float f32x2;

// ---- workspace layout, MFMA path (bytes) ----
#define WS_S        0          // float[32768]
#define WS_E2       131072     // float[8192]
#define WS_CNTS     163840     // float[8192]   counts
#define WS_PART     196608     // float[32768]  loss partials
#define WS_IDX      327680     // int[32768]    final argmin
#define WS_CCNT     458752     // int[32768]    candidate counts
#define WS_CCOL     589824     // int[32768*16] candidate cols
#define WS_EHT      2686976    // ushort[8192*256] E^T in bf16
#define WS_CORE_END 6881280
#define WS_ET       6881280    // float[8192*256]  E^T f32 (optional, gathers)
#define WS_ET_END   15269888
// ---- fallback layout (round-6, proven; S/e2 offsets shared) ----
#define FB_PVAL     163840
#define FB_PIDX     425984
#define FB_CNT      688128
#define FB_PART     720896

#define MARGIN 6.0e-4f
#define CAP 32

__device__ __forceinline__ ushort f2bf(float f) {  // RNE f32->bf16 bits
  uint32_t u = __float_as_uint(f);
  u += 0x7FFF + ((u >> 16) & 1);
  return (ushort)(u >> 16);
}

// ---- shared small kernels (both paths) ----
__global__ void k_sumz(const float* __restrict__ z, float* __restrict__ S) {
  int t = blockIdx.x * blockDim.x + threadIdx.x;
  const float4* zp = (const float4*)(z + (size_t)t * DIM);
  float s = 0.0f;
  #pragma unroll 4
  for (int g = 0; g < DIM / 4; ++g) {
    float4 v = zp[g];
    s = __fadd_rn(s, __fmul_rn(v.x, v.x));
    s = __fadd_rn(s, __fmul_rn(v.y, v.y));
    s = __fadd_rn(s, __fmul_rn(v.z, v.z));
    s = __fadd_rn(s, __fmul_rn(v.w, v.w));
  }
  S[t] = s;
}

// e2 exact value non-critical: fl(S+e2)==S (S~256, e2<4e-6).
__global__ void k_sume(const float* __restrict__ E, float* __restrict__ e2) {
  __shared__ float part[4][64];
  int c  = threadIdx.x & 63;
  int dq = threadIdx.x >> 6;
  int col = blockIdx.x * 64 + c;
  float s = 0.0f;
  #pragma unroll 4
  for (int d = dq * 64; d < dq * 64 + 64; ++d) {
    float v = E[(size_t)d * K_EMB + col];
    s = __fadd_rn(s, __fmul_rn(v, v));
  }
  part[dq][c] = s;
  __syncthreads();
  if (threadIdx.x < 64)
    e2[blockIdx.x * 64 + threadIdx.x] =
        __fadd_rn(__fadd_rn(part[0][threadIdx.x], part[1][threadIdx.x]),
                  __fadd_rn(part[2][threadIdx.x], part[3][threadIdx.x]));
}

// E[256][8192] -> EhT bf16 [8192][256] (+ f32 ET if room). 32x32 tiles.
__global__ void k_prep_et(const float* __restrict__ E, ushort* __restrict__ EhT,
                          float* __restrict__ ET, int useET) {
  __shared__ float tile[32][33];
  int k0 = blockIdx.x * 32, d0 = blockIdx.y * 32;
  int lx = threadIdx.x, ly = threadIdx.y;  // 32 x 8
  #pragma unroll
  for (int r = 0; r < 32; r += 8)
    tile[ly + r][lx] = E[(size_t)(d0 + ly + r) * K_EMB + k0 + lx];
  __syncthreads();
  #pragma unroll
  for (int r = 0; r < 32; r += 8) {
    float v = tile[lx][ly + r];
    size_t o = (size_t)(k0 + ly + r) * DIM + d0 + lx;
    EhT[o] = f2bf(v);
    if (useET) ET[o] = v;
  }
}

// ---- MFMA shortlist kernel ----
// 256 blocks x 256 thr; wave w owns rows blk*128 + w*32 .. +32 (2 row-tiles).
// A-frags (z, bf16) persistent in regs; E^T strip-tiles reg-staged into LDS
// (80B padded rows -> 2-way-free b128 reads); 16 MFMA 16x16x32/K-step/wave.
__global__ __launch_bounds__(256, 1)
void k_mfma(const float* __restrict__ z, const ushort* __restrict__ EhT,
            int* __restrict__ candcnt, int* __restrict__ candcol) {
  __shared__ __align__(16) ushort etile[2][128][40];  // 40 ushort = 80B rows
  __shared__ int   scnt[128];
  __shared__ int   slost[128];
  __shared__ int   scol[128][CAP];
  __shared__ float sval[128][CAP];

  const int tid = threadIdx.x;
  const int l   = tid & 63;
  const int w   = tid >> 6;
  const int rowbase = blockIdx.x * 128;

  if (tid < 128) { scnt[tid] = 0; slost[tid] = 0; }

  // A-frags: lane holds z[row=base+rt*16+(l&15)][k=(l>>4)*8 + 0..7] as bf16.
  short8v az[2][8];
  #pragma unroll
  for (int rt = 0; rt < 2; ++rt) {
    int row = rowbase + w * 32 + rt * 16 + (l & 15);
    const float* zp = z + (size_t)row * DIM;
    #pragma unroll
    for (int ks = 0; ks < 8; ++ks) {
      int d0 = ks * 32 + (l >> 4) * 8;
      float4 a = *(const float4*)(zp + d0);
      float4 b = *(const float4*)(zp + d0 + 4);
      short8v v;
      v[0] = (short)f2bf(a.x); v[1] = (short)f2bf(a.y);
      v[2] = (short)f2bf(a.z); v[3] = (short)f2bf(a.w);
      v[4] = (short)f2bf(b.x); v[5] = (short)f2bf(b.y);
      v[6] = (short)f2bf(b.z); v[7] = (short)f2bf(b.w);
      az[rt][ks] = v;
    }
  }

  float rmin[2][4];
  #pragma unroll
  for (int rt = 0; rt < 2; ++rt)
    #pragma unroll
    for (int r = 0; r < 4; ++r) rmin[rt][r] = 3.402823466e38f;

  // staging: thread stages 32B of one code row: code=tid>>1, half=tid&1
  float4 st0, st1;
  auto LOADG = [&](int col0, int ks) {
    const ushort* p = EhT + (size_t)(col0 + (tid >> 1)) * DIM + ks * 32 + (tid & 1) * 16;
    st0 = *(const float4*)(p);
    st1 = *(const float4*)(p + 8);
  };
  auto STORE = [&](int buf) {
    ushort* d = &etile[buf][tid >> 1][(tid & 1) * 16];
    *(float4*)(d) = st0;
    *(float4*)(d + 8) = st1;
  };

  for (int s = 0; s < 64; ++s) {
    const int col0 = s * 128;
    f32x4 acc[2][8];
    #pragma unroll
    for (int rt = 0; rt < 2; ++rt)
      #pragma unroll
      for (int ct = 0; ct < 8; ++ct)
        acc[rt][ct] = (f32x4){0.f, 0.f, 0.f, 0.f};

    LOADG(col0, 0); STORE(0);
    __syncthreads();

    #pragma unroll
    for (int ks = 0; ks < 8; ++ks) {
      const int buf = ks & 1;
      if (ks < 7) LOADG(col0, ks + 1);
      short8v bf[8];
      #pragma unroll
      for (int ct = 0; ct < 8; ++ct)   // B-frag: code=ct*16+(l&15), k=(l>>4)*8+i
        bf[ct] = *(const short8v*)&etile[buf][ct * 16 + (l & 15)][(l >> 4) * 8];
      #pragma unroll
      for (int rt = 0; rt < 2; ++rt)
        #pragma unroll
        for (int ct = 0; ct < 8; ++ct)
          acc[rt][ct] = __builtin_amdgcn_mfma_f32_16x16x32_bf16(
              az[rt][ks], bf[ct], acc[rt][ct], 0, 0, 0);
      if (ks < 7) STORE(buf ^ 1);
      __syncthreads();
    }

    // epilogue: s_hat = -2*dot; row-min reduce over the 16 lanes sharing the
    // row; append candidates within MARGIN of the running min.
    #pragma unroll
    for (int rt = 0; rt < 2; ++rt) {
      #pragma unroll
      for (int r = 0; r < 4; ++r) {  // D-frag: row=(l>>4)*4+r, col=l&15 (m89)
        float sv[8];
        float m = 3.402823466e38f;
        #pragma unroll
        for (int ct = 0; ct < 8; ++ct) {
          sv[ct] = -2.0f * acc[rt][ct][r];
          m = fminf(m, sv[ct]);
        }
        #pragma unroll
        for (int mk = 1; mk < 16; mk <<= 1) m = fminf(m, __shfl_xor(m, mk));
        float rm = fminf(rmin[rt][r], m);
        rmin[rt][r] = rm;
        float thr = rm + MARGIN;
        int rloc = w * 32 + rt * 16 + (l >> 4) * 4 + r;
        #pragma unroll
        for (int ct = 0; ct < 8; ++ct) {
          if (sv[ct] <= thr) {
            int p = atomicAdd(&scnt[rloc], 1);
            if (p < CAP) {
              scol[rloc][p] = col0 + ct * 16 + (l & 15);
              sval[rloc][p] = sv[ct];
            } else slost[rloc] = 1;
          }
        }
      }
    }
    // per-row compaction (owner lane; rows are wave-private)
    if ((l & 15) == 0) {
      #pragma unroll
      for (int rt = 0; rt < 2; ++rt)
        #pragma unroll
        for (int r = 0; r < 4; ++r) {
          int rloc = w * 32 + rt * 16 + (l >> 4) * 4 + r;
          int c = scnt[rloc];
          if (c > 20) {
            if (c > CAP) c = CAP;
            float th = rmin[rt][r] + MARGIN;
            int k2 = 0;
            for (int j = 0; j < c; ++j) {
              float v = sval[rloc][j];
              if (v <= th) { scol[rloc][k2] = scol[rloc][j]; sval[rloc][k2] = v; ++k2; }
            }
            scnt[rloc] = k2;
          }
        }
    }
  }

  __syncthreads();
  if ((l & 15) == 0) {
    #pragma unroll
    for (int rt = 0; rt < 2; ++rt)
      #pragma unroll
      for (int r = 0; r < 4; ++r) {
        int rloc = w * 32 + rt * 16 + (l >> 4) * 4 + r;
        int grow = rowbase + rloc;
        int c = scnt[rloc];
        int lost = slost[rloc];
        if (c > CAP) { lost = 1; c = CAP; }
        float th = rmin[rt][r] + MARGIN;
        int k2 = 0;
        for (int j = 0; j < c; ++j)
          if (sval[rloc][j] <= th) {
            if (k2 < 16) candcol[(size_t)grow * 16 + k2] = scol[rloc][j];
            ++k2;
          }
        if (k2 > 16) lost = 1;
        candcnt[grow] = lost ? -1 : k2;
      }
  }
}

// exact re-verify: reference-rounded d = fl(fl(S+e2) - 2*fmaf-chain(dot)),
// strict-< with lowest-index tie-break. Full-row scan if shortlist lost.
__global__ void k_rescue(const float* __restrict__ z, const float* __restrict__ E,
                         const float* __restrict__ ET, int useET,
                         const float* __restrict__ S, const float* __restrict__ e2,
                         const int* __restrict__ candcnt, const int* __restrict__ candcol,
                         int* __restrict__ idx) {
  int row = blockIdx.x * 256 + threadIdx.x;
  const float* zr = z + (size_t)row * DIM;
  float Sv = S[row];
  float bestv = 3.402823466e38f;
  int   besti = K_EMB;
  int c = candcnt[row];
  if (c > 0) {
    for (int j = 0; j < c; ++j) {
      int col = candcol[(size_t)row * 16 + j];
      float dot = 0.0f;
      if (useET) {
        const float* ep = ET + (size_t)col * DIM;
        for (int d = 0; d < DIM; ++d) dot = fmaf(zr[d], ep[d], dot);
      } else {
        for (int d = 0; d < DIM; ++d) dot = fmaf(zr[d], E[(size_t)d * K_EMB + col], dot);
      }
      float val = __fsub_rn(__fadd_rn(Sv, e2[col]), __fmul_rn(2.0f, dot));
      if (val < bestv || (val == bestv && col < besti)) { bestv = val; besti = col; }
    }
  } else {  // lost (or empty): exact full scan -- correctness-only path
    for (int col = 0; col < K_EMB; ++col) {
      float dot = 0.0f;
      if (useET) {
        const float* ep = ET + (size_t)col * DIM;
        for (int d = 0; d < DIM; ++d) dot = fmaf(zr[d], ep[d], dot);
      } else {
        for (int d = 0; d < DIM; ++d) dot = fmaf(zr[d], E[(size_t)d * K_EMB + col], dot);
      }
      float val = __fsub_rn(__fadd_rn(Sv, e2[col]), __fmul_rn(2.0f, dot));
      if (val < bestv) { bestv = val; besti = col; }  // ascending order: < keeps lowest
    }
  }
  idx[row] = besti;
}

// straight-through output from precomputed idx (proven body)
__global__ void k_out2(const float* __restrict__ z, const float* __restrict__ E,
                       const float* __restrict__ ET, int useET,
                       const int* __restrict__ idxArr,
                       float* __restrict__ out, float* __restrict__ counts,
                       float* __restrict__ partials) {
  int n = blockIdx.x;
  int t = threadIdx.x;
  int idx = idxArr[n];
  float q  = useET ? ET[(size_t)idx * DIM + t] : E[(size_t)t * K_EMB + idx];
  float zz = z[(size_t)n * DIM + t];
  float dd = __fsub_rn(q, zz);
  out[(size_t)n * DIM + t] = __fadd_rn(zz, dd);
  float sq = __fmul_rn(dd, dd);
  #pragma unroll
  for (int o = 32; o > 0; o >>= 1) sq += __shfl_down(sq, o);
  __shared__ float wsum[4];
  if ((t & 63) == 0) wsum[t >> 6] = sq;
  __syncthreads();
  if (t == 0) {
    partials[n] = ((wsum[0] + wsum[1]) + (wsum[2] + wsum[3]));
    atomicAdd(&counts[idx], 1.0f);
    out[(size_t)N_TOK * DIM + n] = (float)idx;
  }
}

__global__ void k_final(const float* __restrict__ partials,
                        const float* __restrict__ counts,
                        float* __restrict__ out) {
  __shared__ double sd[256];
  int t = threadIdx.x;
  double s = 0.0;
  for (int i = t; i < N_TOK; i += 256) s += (double)partials[i];
  sd[t] = s;
  __syncthreads();
  for (int o = 128; o > 0; o >>= 1) { if (t < o) sd[t] += sd[t + o]; __syncthreads(); }
  double totalLoss = sd[0];
  __syncthreads();
  double s2 = 0.0;
  for (int k = t; k < K_EMB; k += 256) {
    float p = counts[k] * (1.0f / (float)N_TOK);
    s2 += (double)(p * logf(p + 1e-10f));
  }
  sd[t] = s2;
  __syncthreads();
  for (int o = 128; o > 0; o >>= 1) { if (t < o) sd[t] += sd[t + o]; __syncthreads(); }
  if (t == 0) {
    const size_t base = (size_t)N_TOK * DIM + N_TOK;
    out[base + 0] = 0.0f;
    out[base + 1] = 0.25f * (float)(totalLoss / (double)(N_TOK * DIM));
    out[base + 2] = expf(-(float)sd[0]);
  }
}

// ================= fallback: round-6 f32 path (proven, 1630us) =================
__device__ __forceinline__ void pk_fma_blo(f32x2& a, f32x2 zz, f32x2 e) {
  asm("v_pk_fma_f32 %0, %1, %2, %0 op_sel:[0,0,0] op_sel_hi:[0,1,1]"
      : "+v"(a) : "v"(zz), "v"(e));
}
__device__ __forceinline__ void pk_fma_bhi(f32x2& a, f32x2 zz, f32x2 e) {
  asm("v_pk_fma_f32 %0, %1, %2, %0 op_sel:[1,0,0] op_sel_hi:[1,1,1]"
      : "+v"(a) : "v"(zz), "v"(e));
}
__device__ __forceinline__ void gload_lds16(const float* g, float* l) {
  __builtin_amdgcn_global_load_lds(
      (const __attribute__((address_space(1))) void*)g,
      (__attribute__((address_space(3))) void*)l, 16, 0, 0);
}

#define BM 128
#define BN 256
#define BK 16
#define KSTEPS 16
#define NCT 16
#define NSTEP (NCT * KSTEPS)

__global__
__attribute__((amdgpu_flat_work_group_size(256, 256), amdgpu_waves_per_eu(2, 2)))
void k_dist_fb(const float* __restrict__ zsrc, const float* __restrict__ E,
               const float* __restrict__ S, const float* __restrict__ e2,
               float* __restrict__ pval, int* __restrict__ pidx) {
  __shared__ __align__(16) float smem[2 * BK * BM + 2 * BK * BN];
  float* zt = smem;
  float* et = smem + 2 * BK * BM;
  const int tid = threadIdx.x;
  const int tx  = tid & 15;
  const int ty  = tid >> 4;
  const int wv  = tid >> 6;
  const int ln  = tid & 63;
  const int rowblk = blockIdx.x >> 1;
  const int half   = blockIdx.x & 1;
  const int row0    = rowblk * BM;
  const int colbase = half * (NCT * BN);

  f32x2 acc[8][8];
  #pragma unroll
  for (int i = 0; i < 8; ++i)
    #pragma unroll
    for (int jp = 0; jp < 8; ++jp) acc[i][jp] = (f32x2){0.0f, 0.0f};
  float best[8]; int bidx[8];
  #pragma unroll
  for (int i = 0; i < 8; ++i) { best[i] = 3.402823466e38f; bidx[i] = 0; }
  float Sreg[8];
  #pragma unroll
  for (int i = 0; i < 8; ++i)
    Sreg[i] = S[row0 + (i >> 2) * 64 + ty * 4 + (i & 3)];

  auto LOADE = [&](int gs) {
    int ks = gs & (KSTEPS - 1), ct = gs >> 4;
    const float* gsrc = E + (size_t)(ks * BK) * K_EMB + colbase + ct * BN + ln * 4;
    float* lb = et + (gs & 1) * (BK * BN);
    #pragma unroll
    for (int it = 0; it < 4; ++it) {
      int dd = it * 4 + wv;
      gload_lds16(gsrc + (size_t)dd * K_EMB, lb + dd * BN);
    }
  };
  float4 pz[2];
  auto LOADZG = [&](int gs) {
    int d0 = (gs & (KSTEPS - 1)) * BK;
    #pragma unroll
    for (int it = 0; it < 2; ++it) {
      int lq = it * 256 + tid;
      pz[it] = *(const float4*)&zsrc[(size_t)(row0 + (lq >> 2)) * DIM + d0 + (lq & 3) * 4];
    }
  };
  auto STOREZ = [&](int b) {
    float* zb = zt + b * (BK * BM);
    #pragma unroll
    for (int it = 0; it < 2; ++it) {
      int lq = it * 256 + tid;
      int zrow = lq >> 2, zdg = lq & 3;
      zb[(zdg * 4 + 0) * BM + zrow] = pz[it].x;
      zb[(zdg * 4 + 1) * BM + zrow] = pz[it].y;
      zb[(zdg * 4 + 2) * BM + zrow] = pz[it].z;
      zb[(zdg * 4 + 3) * BM + zrow] = pz[it].w;
    }
  };

  LOADE(0); LOADZG(0); STOREZ(0);
  __syncthreads();
  for (int gs = 0; gs < NSTEP; ++gs) {
    const int buf = gs & 1;
    if (gs + 1 < NSTEP) { LOADE(gs + 1); LOADZG(gs + 1); }
    const float* zb = zt + buf * (BK * BM);
    const float* eb = et + buf * (BK * BN);
    #pragma unroll 4
    for (int d = 0; d < BK; ++d) {
      float4 za = *(const float4*)&zb[d * BM + ty * 4];
      float4 zc = *(const float4*)&zb[d * BM + 64 + ty * 4];
      f32x2 ep[8];
      #pragma unroll
      for (int g = 0; g < 4; ++g) {
        float4 wq = *(const float4*)&eb[d * BN + g * 64 + tx * 4];
        ep[2 * g + 0] = (f32x2){wq.x, wq.y};
        ep[2 * g + 1] = (f32x2){wq.z, wq.w};
      }
      f32x2 zp[4] = {(f32x2){za.x, za.y}, (f32x2){za.z, za.w},
                     (f32x2){zc.x, zc.y}, (f32x2){zc.z, zc.w}};
      #pragma unroll
      for (int ip = 0; ip < 4; ++ip)
        #pragma unroll
        for (int jp = 0; jp < 8; ++jp) {
          pk_fma_blo(acc[2 * ip + 0][jp], zp[ip], ep[jp]);
          pk_fma_bhi(acc[2 * ip + 1][jp], zp[ip], ep[jp]);
        }
    }
    if ((gs & (KSTEPS - 1)) == KSTEPS - 1) {
      int col0c = colbase + (gs >> 4) * BN;
      float e2r[16];
      #pragma unroll
      for (int j = 0; j < 16; ++j)
        e2r[j] = e2[col0c + (j >> 2) * 64 + tx * 4 + (j & 3)];
      #pragma unroll
      for (int i = 0; i < 8; ++i)
        #pragma unroll
        for (int j = 0; j < 16; ++j) {
          float dotv = acc[i][j >> 1][j & 1];
          float t1   = __fadd_rn(Sreg[i], e2r[j]);
          float val  = __fsub_rn(t1, __fmul_rn(2.0f, dotv));
          int cidx   = col0c + (j >> 2) * 64 + tx * 4 + (j & 3);
          if (val < best[i]) { best[i] = val; bidx[i] = cidx; }
          acc[i][j >> 1][j & 1] = 0.0f;
        }
    }
    if (gs + 1 < NSTEP) STOREZ(buf ^ 1);
    __syncthreads();
  }
  float* redv = smem;
  int*   redi = (int*)(smem + BM * 16);
  #pragma unroll
  for (int i = 0; i < 8; ++i) {
    int r = (i >> 2) * 64 + ty * 4 + (i & 3);
    redv[r * 16 + tx] = best[i];
    redi[r * 16 + tx] = bidx[i];
  }
  __syncthreads();
  if (tid < BM) {
    float bv = redv[tid * 16];
    int   bi = redi[tid * 16];
    #pragma unroll
    for (int u = 1; u < 16; ++u) {
      float v = redv[tid * 16 + u];
      int  ii = redi[tid * 16 + u];
      if (v < bv || (v == bv && ii < bi)) { bv = v; bi = ii; }
    }
    pval[(size_t)half * N_TOK + row0 + tid] = bv;
    pidx[(size_t)half * N_TOK + row0 + tid] = bi;
  }
}

__global__ void k_out_fb(const float* __restrict__ z, const float* __restrict__ E,
                         const float* __restrict__ pval, const int* __restrict__ pidx,
                         float* __restrict__ out, float* __restrict__ counts,
                         float* __restrict__ partials) {
  int n = blockIdx.x;
  int t = threadIdx.x;
  float bv = pval[n];
  int   bi = pidx[n];
  {
    float v = pval[(size_t)N_TOK + n];
    int  ii = pidx[(size_t)N_TOK + n];
    if (v < bv || (v == bv && ii < bi)) { bv = v; bi = ii; }
  }
  int idx = bi;
  float q  = E[(size_t)t * K_EMB + idx];
  float zz = z[(size_t)n * DIM + t];
  float dd = __fsub_rn(q, zz);
  out[(size_t)n * DIM + t] = __fadd_rn(zz, dd);
  float sq = __fmul_rn(dd, dd);
  #pragma unroll
  for (int o = 32; o > 0; o >>= 1) sq += __shfl_down(sq, o);
  __shared__ float wsum[4];
  if ((t & 63) == 0) wsum[t >> 6] = sq;
  __syncthreads();
  if (t == 0) {
    partials[n] = ((wsum[0] + wsum[1]) + (wsum[2] + wsum[3]));
    atomicAdd(&counts[idx], 1.0f);
    out[(size_t)N_TOK * DIM + n] = (float)idx;
  }
}

extern "C" void kernel_launch(void* const* d_in, const int* in_sizes, int n_in,
                              void* d_out, int out_size, void* d_ws, size_t ws_size,
                              hipStream_t stream) {
  const float* z = (const float*)d_in[0];
  const float* E = (const float*)d_in[1];
  float* out = (float*)d_out;
  char* w = (char*)d_ws;
  float* S  = (float*)(w + WS_S);
  float* e2 = (float*)(w + WS_E2);

  const int useMFMA = (ws_size >= (size_t)WS_CORE_END) ? 1 : 0;
  const int useET   = (ws_size >= (size_t)WS_ET_END) ? 1 : 0;

  if (useMFMA) {
    float*  counts   = (float*)(w + WS_CNTS);
    float*  partials = (float*)(w + WS_PART);
    int*    idx      = (int*)(w + WS_IDX);
    int*    candcnt  = (int*)(w + WS_CCNT);
    int*    candcol  = (int*)(w + WS_CCOL);
    ushort* EhT      = (ushort*)(w + WS_EHT);
    float*  ET       = (float*)(w + WS_ET);

    hipMemsetAsync(w + WS_CNTS, 0, K_EMB * sizeof(float), stream);
    k_sumz<<<N_TOK / 256, 256, 0, stream>>>(z, S);
    k_sume<<<K_EMB / 64, 256, 0, stream>>>(E, e2);
    k_prep_et<<<dim3(K_EMB / 32, DIM / 32), dim3(32, 8), 0, stream>>>(E, EhT, ET, useET);
    k_mfma<<<N_TOK / 128, 256, 0, stream>>>(z, EhT, candcnt, candcol);
    k_rescue<<<N_TOK / 256, 256, 0, stream>>>(z, E, ET, useET, S, e2, candcnt, candcol, idx);
    k_out2<<<N_TOK, 256, 0, stream>>>(z, E, ET, useET, idx, out, counts, partials);
    k_final<<<1, 256, 0, stream>>>(partials, counts, out);
  } else {
    float* pval     = (float*)(w + FB_PVAL);
    int*   pidx     = (int*)(w + FB_PIDX);
    float* counts   = (float*)(w + FB_CNT);
    float* partials = (float*)(w + FB_PART);

    hipMemsetAsync(w + FB_CNT, 0, K_EMB * sizeof(float), stream);
    k_sumz<<<N_TOK / 256, 256, 0, stream>>>(z, S);
    k_sume<<<K_EMB / 64, 256, 0, stream>>>(E, e2);
    k_dist_fb<<<512, 256, 0, stream>>>(z, E, S, e2, pval, pidx);
    k_out_fb<<<N_TOK, 256, 0, stream>>>(z, E, pval, pidx, out, counts, partials);
    k_final<<<1, 256, 0, stream>>>(partials, counts, out);
  }
}